// Round 19
// baseline (362.007 us; speedup 1.0000x reference)
//
#include <hip/hip_runtime.h>
#include <math.h>

#define HW    9216
#define HDIM  96
#define WDIM  96
#define NIMG  8
#define CF    64
#define OFFCH 144
#define MSKCH 72
#define OMC   216
#define NT    36
#define TSTR  44    // MODE0 epilogue transpose stride (u16)
#define HBUF  10368 // halo buffer size in u16 (1296 x 8)

typedef unsigned short u16;
typedef unsigned int   u32;
typedef _Float16 f16;
typedef __attribute__((ext_vector_type(8))) _Float16 f16x8;
typedef __attribute__((ext_vector_type(4))) float f32x4;
typedef __attribute__((ext_vector_type(4))) u32 u32x4;
typedef __attribute__((address_space(1))) const u32 g_u32;
typedef __attribute__((address_space(3))) u32 l_u32;

__device__ inline u16 f16b(f16 h){ u16 r; __builtin_memcpy(&r, &h, 2); return r; }
__device__ inline f16 b16f(u16 b){ f16 h; __builtin_memcpy(&h, &b, 2); return h; }

// ---- weight prepack (same as R12) -------------------------------------------
__global__ void pack_w_k(const float* __restrict__ bw,
                         const float* __restrict__ ow0, const float* __restrict__ ow1,
                         const float* __restrict__ ow2, const float* __restrict__ ow3,
                         const float* __restrict__ dw0, const float* __restrict__ dw1,
                         const float* __restrict__ dw2, const float* __restrict__ dw3,
                         u16* __restrict__ wp, float* __restrict__ dwp)
{
    const float* ows[4] = {ow0, ow1, ow2, ow3};
    const float* dws[4] = {dw0, dw1, dw2, dw3};
    int total = 73728 + 4 * 124416;
    for (int j = blockIdx.x * blockDim.x + threadIdx.x; j < total;
         j += gridDim.x * blockDim.x) {
        if (j < 73728) {                      // bneck src [oc][ci][tap]
            int oc = j / 1152, r = j % 1152, ci = r / 9, tap = r % 9;
            wp[(size_t)(oc * 9 + tap) * 128 + ci] = f16b((f16)bw[j]);
        } else {
            int k = j - 73728;
            int layer = k / 124416, r = k % 124416;
            int oc = r / 576, r3 = r % 576, ci = r3 / 9, tap = r3 % 9;
            wp[73728 + (size_t)layer * 129024 + (size_t)(oc * 9 + tap) * 64 + ci] =
                f16b((f16)ows[layer][r]);
        }
    }
    for (int j = blockIdx.x * blockDim.x + threadIdx.x; j < 4 * 4608;
         j += gridDim.x * blockDim.x) {
        int layer = j / 4608, e = j % 4608;
        wp[73728 + (size_t)layer * 129024 + 124416 + e] = 0;
    }
    for (int j = blockIdx.x * blockDim.x + threadIdx.x; j < 4 * 8 * 576;
         j += gridDim.x * blockDim.x) {
        int layer = j / 4608, r = j % 4608, g = r / 576, e = r % 576;
        int kk = e / 64, c = (e / 8) % 8, o = e % 8;
        dwp[j] = dws[layer][(size_t)(g * 8 + o) * 72 + c * 9 + kk];
    }
}

// ---- concat -> blocked cat [n][tile][16pl][256px][8c] (same as R12) ---------
__global__ __launch_bounds__(256) void prep_cat_k(
    const float* __restrict__ burst, u16* __restrict__ cat)
{
    __shared__ float tb[32 * 257];
    const int id = blockIdx.x;
    const int n = id & 7, tile = id >> 3;      // image-per-XCD
    const int oy = (tile / 6) * 16, ox = (tile % 6) * 16;
    const int tid = threadIdx.x;

    for (int pass = 0; pass < 4; ++pass) {
        const float* src = (pass < 2) ? burst + (size_t)n * CF * HW : burst;
        const int chb = (pass & 1) * 32;
        __syncthreads();
        {
            int c = tid >> 3, q = tid & 7;
            const float* sp = src + (size_t)(chb + c) * HW;
#pragma unroll
            for (int rr = 0; rr < 2; ++rr) {
                int row = q * 2 + rr;
                const float* rp = sp + (oy + row) * WDIM + ox;
#pragma unroll
                for (int jj = 0; jj < 4; ++jj) {
                    f32x4 v = *(const f32x4*)(rp + jj * 4);
                    int px = row * 16 + jj * 4;
                    tb[c * 257 + px + 0] = v.x;
                    tb[c * 257 + px + 1] = v.y;
                    tb[c * 257 + px + 2] = v.z;
                    tb[c * 257 + px + 3] = v.w;
                }
            }
        }
        __syncthreads();
        {
            int p = tid;
#pragma unroll
            for (int cq = 0; cq < 4; ++cq) {
                u32 wd[4];
#pragma unroll
                for (int e = 0; e < 4; ++e) {
                    int c0 = cq * 8 + e * 2;
                    u16 h0 = f16b((f16)tb[c0 * 257 + p]);
                    u16 h1 = f16b((f16)tb[(c0 + 1) * 257 + p]);
                    wd[e] = (u32)h0 | ((u32)h1 << 16);
                }
                u32x4 hv = {wd[0], wd[1], wd[2], wd[3]};
                int plane = pass * 4 + cq;
                *(u32x4*)(cat + ((size_t)((n * NT + tile) * 16 + plane) * 256 + p) * 8) = hv;
            }
        }
    }
}

// ---- MFMA implicit-GEMM conv3x3 (fp16, double-buffered async staging) -------
// Two linear halo buffers (1296 x 16B each). Prologue stages buf0; each chunk:
// barrier (drains current DMA) -> issue next chunk into other buf -> tap loop.
// Next chunk's DMA is in flight across the whole compute phase.
template<int PLANES, int MODE>
__global__ __launch_bounds__(256, 4) void conv_mfma_k(
    const u16* __restrict__ inb,   // blocked [n][NT][PLANES][256][8]
    const u16* __restrict__ w_hi,  // [oc][9][CIN] fp16
    u16* __restrict__ om_out,      // MODE1: [n][NT][216][256] fp16
    u16* __restrict__ out_feat)    // MODE0: [n][NT][8][256][8] fp16
{
    __shared__ __align__(16) u16 lds[2 * HBUF];   // 41472 B (epilogue reuses)

    const int CIN = PLANES * 8;
    const int NCH = PLANES / 4;
    const int id = blockIdx.x;
    const int n = id & 7, w = id >> 3;
    const int tile = (MODE == 0) ? (w >> 1) : (w / 7);
    const int ocg  = (MODE == 0) ? (w & 1)  : (w % 7);
    const int tid = threadIdx.x;
    const int wv = tid >> 6, lane = tid & 63;
    const int lx = lane & 15, lg = lane >> 4;
    const int oy = (tile / 6) * 16, ox = (tile % 6) * 16;

    f32x4 acc[2][4];
#pragma unroll
    for (int t = 0; t < 2; ++t)
#pragma unroll
        for (int r = 0; r < 4; ++r)
            acc[t][r] = (f32x4){0.f, 0.f, 0.f, 0.f};

    // pre-zero BOTH halo buffers once (boundary cells stay zero: masked DMA
    // lanes never overwrite them)
    for (int u = tid; u < 2592; u += 256)
        *(u32x4*)(lds + u * 8) = (u32x4){0u, 0u, 0u, 0u};
    __syncthreads();

    const u16* inb_n = inb + (size_t)(n * NT) * PLANES * 2048;
    const u16* wr0 = w_hi + (size_t)((ocg * 32 + lx) * 9) * CIN + lg * 8;
    const u16* wr1 = w_hi + (size_t)((ocg * 32 + 16 + lx) * 9) * CIN + lg * 8;

    auto stage = [&](int buf, int chk) {
#pragma unroll
        for (int it = 0; it < 6; ++it) {
            int u = it * 256 + tid;
            u16* ldsbase = lds + (size_t)buf * HBUF + (size_t)(it * 256 + wv * 64) * 8;
            if (u < 1296) {
                int plane = u / 324, pos = u - plane * 324;
                int yy = pos / 18, xx = pos - yy * 18;
                int gy = oy + yy - 1, gx = ox + xx - 1;
                if (gy >= 0 && gy < HDIM && gx >= 0 && gx < WDIM) {
                    int tof = (gy >> 4) * 6 + (gx >> 4);
                    int pin = (gy & 15) * 16 + (gx & 15);
                    const u16* src = inb_n +
                        ((size_t)(tof * PLANES + chk * 4 + plane) * 256 + pin) * 8;
                    __builtin_amdgcn_global_load_lds((g_u32*)src, (l_u32*)ldsbase, 16, 0, 0);
                }
            }
        }
    };

    stage(0, 0);   // prologue

    for (int chk = 0; chk < NCH; ++chk) {
        __syncthreads();                       // drains chunk chk's DMA
        if (chk + 1 < NCH) stage((chk + 1) & 1, chk + 1);   // async prefetch

        const int buf = chk & 1;
        const u16* wc0 = wr0 + chk * 32;
        const u16* wc1 = wr1 + chk * 32;
        const u16* lbase = lds + (size_t)buf * HBUF + (size_t)lg * 324 * 8;

        // prologue: tap-0 weights + B-fragments
        f16x8 aw0 = *(const f16x8*)(wc0);
        f16x8 aw1 = *(const f16x8*)(wc1);
        f16x8 bfr[4];
#pragma unroll
        for (int r = 0; r < 4; ++r)
            bfr[r] = *(const f16x8*)(lbase + ((wv * 4 + r) * 18 + lx) * 8);

#pragma unroll
        for (int tap = 0; tap < 9; ++tap) {
            f16x8 na0, na1, nb[4];
            if (tap < 8) {
                const int ntap = tap + 1;
                const int nky = ntap / 3, nkx = ntap - nky * 3;
                na0 = *(const f16x8*)(wc0 + (size_t)ntap * CIN);
                na1 = *(const f16x8*)(wc1 + (size_t)ntap * CIN);
#pragma unroll
                for (int r = 0; r < 4; ++r)
                    nb[r] = *(const f16x8*)(lbase + ((wv * 4 + r + nky) * 18 + lx + nkx) * 8);
            }
#pragma unroll
            for (int r = 0; r < 4; ++r) {
                acc[0][r] = __builtin_amdgcn_mfma_f32_16x16x32_f16(aw0, bfr[r], acc[0][r], 0, 0, 0);
                acc[1][r] = __builtin_amdgcn_mfma_f32_16x16x32_f16(aw1, bfr[r], acc[1][r], 0, 0, 0);
            }
            if (tap < 8) {
                aw0 = na0; aw1 = na1;
#pragma unroll
                for (int r = 0; r < 4; ++r) bfr[r] = nb[r];
            }
        }
    }

    if (MODE == 0) {
        // transpose to [px][ch] then dense per-plane stores (R12 epilogue)
        __syncthreads();
        u16* tb = lds;                         // [256][TSTR]
#pragma unroll
        for (int t = 0; t < 2; ++t)
#pragma unroll
            for (int r = 0; r < 4; ++r) {
                int px = (wv * 4 + r) * 16 + lx;
#pragma unroll
                for (int v = 0; v < 4; ++v)
                    tb[px * TSTR + t * 16 + lg * 4 + v] = f16b((f16)acc[t][r][v]);
            }
        __syncthreads();
        const int p = tid;
        const u16* srcr = tb + p * TSTR;
#pragma unroll
        for (int cq = 0; cq < 4; ++cq) {
            *(u32x4*)(out_feat + ((size_t)((n * NT + tile) * 8 + ocg * 4 + cq) * 256 + p) * 8)
                = *(const u32x4*)(srcr + cq * 8);
        }
    } else {
        // transpose to [ch][px] fp16 (sigmoid fused), 128B-dense row stores
        __syncthreads();
        u16* tb = lds;                         // [32][264]
#pragma unroll
        for (int t = 0; t < 2; ++t) {
            const bool sig = (ocg * 32 + t * 16) >= OFFCH;  // 144 % 16 == 0
#pragma unroll
            for (int r = 0; r < 4; ++r) {
                int px = (wv * 4 + r) * 16 + lx;
#pragma unroll
                for (int v = 0; v < 4; ++v) {
                    float val = acc[t][r][v];
                    if (sig) val = 1.f / (1.f + __expf(-val));
                    tb[(t * 16 + lg * 4 + v) * 264 + px] = f16b((f16)val);
                }
            }
        }
        __syncthreads();
        const int ocl = tid >> 3, q = tid & 7;
        const int ch = ocg * 32 + ocl;
        if (ch < OMC) {
            u16* dst = om_out + ((size_t)(n * NT + tile) * OMC + ch) * 256;
            const u16* srcr = tb + ocl * 264;
#pragma unroll
            for (int j = 0; j < 4; ++j) {
                int un = (q + j * 8) * 8;
                *(u32x4*)(dst + un) = *(const u32x4*)(srcr + un);
            }
        }
    }
}

// ---- modulated deformable conv; blocked om (fp16) + blocked feat (R12) ------
template<int LAST>
__global__ __launch_bounds__(256, 4) void deform_k(
    const u16* __restrict__ feat,  // [n][NT][8][256][8] fp16
    const u16* __restrict__ om,    // [n][NT][216][256] fp16
    const float* __restrict__ wgtp, const float* __restrict__ bias,
    u16* __restrict__ out_feat, float* __restrict__ out32)
{
    const int id = blockIdx.x;
    const int n = id & 7, w = id >> 3;
    const int tile = w >> 3, g = w & 7;        // tile-major, g fastest

    const int ty = threadIdx.x >> 4, tx = threadIdx.x & 15;
    const int h  = (tile / 6) * 16 + ty;
    const int wx = (tile % 6) * 16 + tx;
    const int pix = h * WDIM + wx;
    const int pixT = ty * 16 + tx;

    const float* wg = wgtp + (size_t)g * 576;
    const u16* ob = om + (size_t)(n * NT + tile) * OMC * 256;
    const u16* fbase = feat + (size_t)(n * NT) * 8 * 2048 + g * 2048;

    float acc[8];
#pragma unroll
    for (int o = 0; o < 8; ++o) acc[o] = 0.f;

#pragma unroll
    for (int k = 0; k < 9; ++k) {
        float dy = (float)b16f(ob[(g * 18 + 2 * k    ) * 256 + pixT]);
        float dx = (float)b16f(ob[(g * 18 + 2 * k + 1) * 256 + pixT]);
        float m  = (float)b16f(ob[(OFFCH + g * 9 + k) * 256 + pixT]);

        float py = dy + (float)(k / 3 - 1) + (float)h;
        float px = dx + (float)(k % 3 - 1) + (float)wx;
        float y0f = floorf(py), x0f = floorf(px);
        float ly = py - y0f, lx = px - x0f;
        int y0 = (int)y0f, x0 = (int)x0f;
        int y1 = y0 + 1,   x1 = x0 + 1;

        bool vy0 = (y0 >= 0) && (y0 < HDIM);
        bool vy1 = (y1 >= 0) && (y1 < HDIM);
        bool vx0 = (x0 >= 0) && (x0 < WDIM);
        bool vx1 = (x1 >= 0) && (x1 < WDIM);

        float w00 = (vy0 && vx0) ? (1.f - ly) * (1.f - lx) : 0.f;
        float w01 = (vy0 && vx1) ? (1.f - ly) * lx         : 0.f;
        float w10 = (vy1 && vx0) ? ly * (1.f - lx)         : 0.f;
        float w11 = (vy1 && vx1) ? ly * lx                 : 0.f;

        int y0c = min(max(y0, 0), HDIM - 1), y1c = min(max(y1, 0), HDIM - 1);
        int x0c = min(max(x0, 0), WDIM - 1), x1c = min(max(x1, 0), WDIM - 1);

        auto ga = [&](int y, int x) -> const f16x8* {
            int tof = (y >> 4) * 6 + (x >> 4);
            int pin = (y & 15) * 16 + (x & 15);
            return (const f16x8*)(fbase + (size_t)tof * 16384 + pin * 8);
        };
        f16x8 C00 = *ga(y0c, x0c);
        f16x8 C01 = *ga(y0c, x1c);
        f16x8 C10 = *ga(y1c, x0c);
        f16x8 C11 = *ga(y1c, x1c);

#pragma unroll
        for (int c = 0; c < 8; ++c) {
            float v =      w00 * (float)C00[c];
            v = fmaf(w01, (float)C01[c], v);
            v = fmaf(w10, (float)C10[c], v);
            v = fmaf(w11, (float)C11[c], v);
            v *= m;
            const float* w8 = wg + (k * 8 + c) * 8;
#pragma unroll
            for (int o = 0; o < 8; ++o)
                acc[o] = fmaf(w8[o], v, acc[o]);
        }
    }

    if (LAST) {
#pragma unroll
        for (int o = 0; o < 8; ++o)
            out32[((size_t)n * CF + g * 8 + o) * HW + pix] = acc[o] + bias[g * 8 + o];
    } else {
        u16 hb[8];
#pragma unroll
        for (int o = 0; o < 8; ++o)
            hb[o] = f16b((f16)(acc[o] + bias[g * 8 + o]));
        u32x4 hv;
        hv.x = (u32)hb[0] | ((u32)hb[1] << 16); hv.y = (u32)hb[2] | ((u32)hb[3] << 16);
        hv.z = (u32)hb[4] | ((u32)hb[5] << 16); hv.w = (u32)hb[6] | ((u32)hb[7] << 16);
        *(u32x4*)(out_feat + ((size_t)((n * NT + tile) * 8 + g) * 256 + pixT) * 8) = hv;
    }
}

// ---------------------------------------------------------------------------
extern "C" void kernel_launch(void* const* d_in, const int* in_sizes, int n_in,
                              void* d_out, int out_size, void* d_ws, size_t ws_size,
                              hipStream_t stream) {
    const float* burst = (const float*)d_in[0];
    const float* bw    = (const float*)d_in[1];

    const float* ow[4]; const float* dw[4]; const float* db[4];
    bool interleaved = (in_sizes[3] == 64 * 8 * 9);
    for (int i = 0; i < 4; ++i) {
        if (interleaved) {
            ow[i] = (const float*)d_in[2 + 3 * i];
            dw[i] = (const float*)d_in[3 + 3 * i];
            db[i] = (const float*)d_in[4 + 3 * i];
        } else {
            ow[i] = (const float*)d_in[2 + i];
            dw[i] = (const float*)d_in[6 + i];
            db[i] = (const float*)d_in[10 + i];
        }
    }

    float* out = (float*)d_out;

    // ws layout (~42.6 MB)
    u16*   om    = (u16*)d_ws;                     // 15,925,248 u16 (31.9MB)
    u16*   featB = om + 15925248;                  //  4,718,592 u16
    u16*   wp    = featB + 4718592;                //    589,824 u16
    float* dwp   = (float*)(wp + 589824);          //     18,432 f32
    u16*   cat   = (u16*)d_ws;                     //  9,437,184 u16 (alias om)
    u16*   featA = (u16*)d_out;                    //  4,718,592 u16 (alias d_out)

    const u16* wp_b = wp;
    const u16* wp_o[4];
    for (int i = 0; i < 4; ++i)
        wp_o[i] = wp + 73728 + (size_t)i * 129024;

    pack_w_k<<<dim3(512), dim3(256), 0, stream>>>(
        bw, ow[0], ow[1], ow[2], ow[3], dw[0], dw[1], dw[2], dw[3], wp, dwp);
    prep_cat_k<<<dim3(288), dim3(256), 0, stream>>>(burst, cat);

    // bottleneck: cat -> featA (d_out alias). 576 = 8 img x (36 tiles x 2 ocg)
    conv_mfma_k<16, 0><<<dim3(576), dim3(256), 0, stream>>>(
        cat, wp_b, nullptr, featA);

    // ping-pong: A -> B -> A -> B -> d_out(fp32)
    u16* fx = featA;
    u16* fy = featB;
    for (int i = 0; i < 4; ++i) {
        conv_mfma_k<8, 1><<<dim3(2016), dim3(256), 0, stream>>>(
            fx, wp_o[i], om, nullptr);
        if (i < 3) {
            deform_k<0><<<dim3(2304), dim3(256), 0, stream>>>(
                fx, om, dwp + (size_t)i * 4608, db[i], fy, nullptr);
            u16* t = fx; fx = fy; fy = t;
        } else {
            deform_k<1><<<dim3(2304), dim3(256), 0, stream>>>(
                fx, om, dwp + (size_t)i * 4608, db[i], nullptr, out);
        }
    }
}

// Round 20
// 339.277 us; speedup vs baseline: 1.0670x; 1.0670x over previous
//
#include <hip/hip_runtime.h>
#include <math.h>

#define HW    9216
#define HDIM  96
#define WDIM  96
#define NIMG  8
#define CF    64
#define OFFCH 144
#define MSKCH 72
#define OMC   216
#define NT    36
#define TSTR  44    // MODE0 epilogue transpose stride (u16)

typedef unsigned short u16;
typedef unsigned int   u32;
typedef _Float16 f16;
typedef __attribute__((ext_vector_type(8))) _Float16 f16x8;
typedef __attribute__((ext_vector_type(4))) float f32x4;
typedef __attribute__((ext_vector_type(4))) u32 u32x4;
typedef __attribute__((address_space(1))) const u32 g_u32;
typedef __attribute__((address_space(3))) u32 l_u32;

__device__ inline u16 f16b(f16 h){ u16 r; __builtin_memcpy(&r, &h, 2); return r; }
__device__ inline f16 b16f(u16 b){ f16 h; __builtin_memcpy(&h, &b, 2); return h; }

// ---- weight prepack (same as R12) -------------------------------------------
__global__ void pack_w_k(const float* __restrict__ bw,
                         const float* __restrict__ ow0, const float* __restrict__ ow1,
                         const float* __restrict__ ow2, const float* __restrict__ ow3,
                         const float* __restrict__ dw0, const float* __restrict__ dw1,
                         const float* __restrict__ dw2, const float* __restrict__ dw3,
                         u16* __restrict__ wp, float* __restrict__ dwp)
{
    const float* ows[4] = {ow0, ow1, ow2, ow3};
    const float* dws[4] = {dw0, dw1, dw2, dw3};
    int total = 73728 + 4 * 124416;
    for (int j = blockIdx.x * blockDim.x + threadIdx.x; j < total;
         j += gridDim.x * blockDim.x) {
        if (j < 73728) {                      // bneck src [oc][ci][tap]
            int oc = j / 1152, r = j % 1152, ci = r / 9, tap = r % 9;
            wp[(size_t)(oc * 9 + tap) * 128 + ci] = f16b((f16)bw[j]);
        } else {
            int k = j - 73728;
            int layer = k / 124416, r = k % 124416;
            int oc = r / 576, r3 = r % 576, ci = r3 / 9, tap = r3 % 9;
            wp[73728 + (size_t)layer * 129024 + (size_t)(oc * 9 + tap) * 64 + ci] =
                f16b((f16)ows[layer][r]);
        }
    }
    for (int j = blockIdx.x * blockDim.x + threadIdx.x; j < 4 * 4608;
         j += gridDim.x * blockDim.x) {
        int layer = j / 4608, e = j % 4608;
        wp[73728 + (size_t)layer * 129024 + 124416 + e] = 0;
    }
    for (int j = blockIdx.x * blockDim.x + threadIdx.x; j < 4 * 8 * 576;
         j += gridDim.x * blockDim.x) {
        int layer = j / 4608, r = j % 4608, g = r / 576, e = r % 576;
        int kk = e / 64, c = (e / 8) % 8, o = e % 8;
        dwp[j] = dws[layer][(size_t)(g * 8 + o) * 72 + c * 9 + kk];
    }
}

// ---- concat -> blocked cat [n][tile][16pl][256px][8c] (same as R12) ---------
__global__ __launch_bounds__(256) void prep_cat_k(
    const float* __restrict__ burst, u16* __restrict__ cat)
{
    __shared__ float tb[32 * 257];
    const int id = blockIdx.x;
    const int n = id & 7, tile = id >> 3;      // image-per-XCD
    const int oy = (tile / 6) * 16, ox = (tile % 6) * 16;
    const int tid = threadIdx.x;

    for (int pass = 0; pass < 4; ++pass) {
        const float* src = (pass < 2) ? burst + (size_t)n * CF * HW : burst;
        const int chb = (pass & 1) * 32;
        __syncthreads();
        {
            int c = tid >> 3, q = tid & 7;
            const float* sp = src + (size_t)(chb + c) * HW;
#pragma unroll
            for (int rr = 0; rr < 2; ++rr) {
                int row = q * 2 + rr;
                const float* rp = sp + (oy + row) * WDIM + ox;
#pragma unroll
                for (int jj = 0; jj < 4; ++jj) {
                    f32x4 v = *(const f32x4*)(rp + jj * 4);
                    int px = row * 16 + jj * 4;
                    tb[c * 257 + px + 0] = v.x;
                    tb[c * 257 + px + 1] = v.y;
                    tb[c * 257 + px + 2] = v.z;
                    tb[c * 257 + px + 3] = v.w;
                }
            }
        }
        __syncthreads();
        {
            int p = tid;
#pragma unroll
            for (int cq = 0; cq < 4; ++cq) {
                u32 wd[4];
#pragma unroll
                for (int e = 0; e < 4; ++e) {
                    int c0 = cq * 8 + e * 2;
                    u16 h0 = f16b((f16)tb[c0 * 257 + p]);
                    u16 h1 = f16b((f16)tb[(c0 + 1) * 257 + p]);
                    wd[e] = (u32)h0 | ((u32)h1 << 16);
                }
                u32x4 hv = {wd[0], wd[1], wd[2], wd[3]};
                int plane = pass * 4 + cq;
                *(u32x4*)(cat + ((size_t)((n * NT + tile) * 16 + plane) * 256 + p) * 8) = hv;
            }
        }
    }
}

// ---- MFMA implicit-GEMM conv3x3 (fp16, global_load_lds async staging) -------
// Halo LDS is LINEAR [4 planes][324 pos][8 u16] (20.25KB, no pad; wave64 b128
// reads hit every bank 8x = conflict-free minimum). Staged via
// __builtin_amdgcn_global_load_lds width=16: wave-uniform LDS base + lane*16,
// per-lane global src; OOB lanes exec-masked, their cells pre-zeroed ONCE
// (masked DMA never overwrites them -> zeros persist across chunks).
template<int PLANES, int MODE>
__global__ __launch_bounds__(256, 4) void conv_mfma_k(
    const u16* __restrict__ inb,   // blocked [n][NT][PLANES][256][8]
    const u16* __restrict__ w_hi,  // [oc][9][CIN] fp16
    u16* __restrict__ om_out,      // MODE1: [n][NT][216][256] fp16
    u16* __restrict__ out_feat)    // MODE0: [n][NT][8][256][8] fp16
{
    __shared__ __align__(16) u16 lds[11264];   // max(halo 10368, tb 11264) u16

    const int CIN = PLANES * 8;
    const int id = blockIdx.x;
    const int n = id & 7, w = id >> 3;
    const int tile = (MODE == 0) ? (w >> 1) : (w / 7);
    const int ocg  = (MODE == 0) ? (w & 1)  : (w % 7);
    const int tid = threadIdx.x;
    const int wv = tid >> 6, lane = tid & 63;
    const int lx = lane & 15, lg = lane >> 4;
    const int oy = (tile / 6) * 16, ox = (tile % 6) * 16;

    f32x4 acc[2][4];
#pragma unroll
    for (int t = 0; t < 2; ++t)
#pragma unroll
        for (int r = 0; r < 4; ++r)
            acc[t][r] = (f32x4){0.f, 0.f, 0.f, 0.f};

    // pre-zero halo region once (boundary cells stay zero for all chunks)
    for (int u = tid; u < 1296; u += 256)
        *(u32x4*)(lds + u * 8) = (u32x4){0u, 0u, 0u, 0u};

    const u16* inb_n = inb + (size_t)(n * NT) * PLANES * 2048;
    const u16* wr0 = w_hi + (size_t)((ocg * 32 + lx) * 9) * CIN + lg * 8;
    const u16* wr1 = w_hi + (size_t)((ocg * 32 + 16 + lx) * 9) * CIN + lg * 8;

    for (int chk = 0; chk < PLANES / 4; ++chk) {
        __syncthreads();
        // async stage: 1296 16B units = [plane 0..3][pos 0..323]
#pragma unroll
        for (int it = 0; it < 6; ++it) {
            int u = it * 256 + tid;
            u16* ldsbase = lds + (size_t)(it * 256 + wv * 64) * 8; // wave-uniform
            if (u < 1296) {
                int plane = u / 324, pos = u - plane * 324;
                int yy = pos / 18, xx = pos - yy * 18;
                int gy = oy + yy - 1, gx = ox + xx - 1;
                if (gy >= 0 && gy < HDIM && gx >= 0 && gx < WDIM) {
                    int tof = (gy >> 4) * 6 + (gx >> 4);
                    int pin = (gy & 15) * 16 + (gx & 15);
                    const u16* src = inb_n +
                        ((size_t)(tof * PLANES + chk * 4 + plane) * 256 + pin) * 8;
                    __builtin_amdgcn_global_load_lds((g_u32*)src, (l_u32*)ldsbase, 16, 0, 0);
                }
            }
        }
        __syncthreads();   // compiler drains vmcnt before the barrier

        const u16* wc0 = wr0 + chk * 32;
        const u16* wc1 = wr1 + chk * 32;
        const u16* lbase = lds + (size_t)lg * 324 * 8;  // plane = lg

        // prologue: tap-0 weights
        f16x8 aw0 = *(const f16x8*)(wc0);
        f16x8 aw1 = *(const f16x8*)(wc1);
        f16x8 bfr[4];
#pragma unroll
        for (int r = 0; r < 4; ++r)
            bfr[r] = *(const f16x8*)(lbase + ((wv * 4 + r + 0) * 18 + lx + 0) * 8);

#pragma unroll
        for (int tap = 0; tap < 9; ++tap) {
            f16x8 na0, na1, nb[4];
            if (tap < 8) {
                const int ntap = tap + 1;
                const int nky = ntap / 3, nkx = ntap - nky * 3;
                na0 = *(const f16x8*)(wc0 + (size_t)ntap * CIN);
                na1 = *(const f16x8*)(wc1 + (size_t)ntap * CIN);
#pragma unroll
                for (int r = 0; r < 4; ++r)
                    nb[r] = *(const f16x8*)(lbase + ((wv * 4 + r + nky) * 18 + lx + nkx) * 8);
            }
#pragma unroll
            for (int r = 0; r < 4; ++r) {
                acc[0][r] = __builtin_amdgcn_mfma_f32_16x16x32_f16(aw0, bfr[r], acc[0][r], 0, 0, 0);
                acc[1][r] = __builtin_amdgcn_mfma_f32_16x16x32_f16(aw1, bfr[r], acc[1][r], 0, 0, 0);
            }
            if (tap < 8) {
                aw0 = na0; aw1 = na1;
#pragma unroll
                for (int r = 0; r < 4; ++r) bfr[r] = nb[r];
            }
        }
    }

    if (MODE == 0) {
        // transpose to [px][ch] then dense per-plane stores (R12 epilogue)
        __syncthreads();
        u16* tb = lds;                         // [256][TSTR]
#pragma unroll
        for (int t = 0; t < 2; ++t)
#pragma unroll
            for (int r = 0; r < 4; ++r) {
                int px = (wv * 4 + r) * 16 + lx;
#pragma unroll
                for (int v = 0; v < 4; ++v)
                    tb[px * TSTR + t * 16 + lg * 4 + v] = f16b((f16)acc[t][r][v]);
            }
        __syncthreads();
        const int p = tid;
        const u16* srcr = tb + p * TSTR;
#pragma unroll
        for (int cq = 0; cq < 4; ++cq) {
            *(u32x4*)(out_feat + ((size_t)((n * NT + tile) * 8 + ocg * 4 + cq) * 256 + p) * 8)
                = *(const u32x4*)(srcr + cq * 8);
        }
    } else {
        // transpose to [ch][px] fp16 (sigmoid fused), 128B-dense row stores
        __syncthreads();
        u16* tb = lds;                         // [32][264]
#pragma unroll
        for (int t = 0; t < 2; ++t) {
            const bool sig = (ocg * 32 + t * 16) >= OFFCH;  // 144 % 16 == 0
#pragma unroll
            for (int r = 0; r < 4; ++r) {
                int px = (wv * 4 + r) * 16 + lx;
#pragma unroll
                for (int v = 0; v < 4; ++v) {
                    float val = acc[t][r][v];
                    if (sig) val = 1.f / (1.f + __expf(-val));
                    tb[(t * 16 + lg * 4 + v) * 264 + px] = f16b((f16)val);
                }
            }
        }
        __syncthreads();
        const int ocl = tid >> 3, q = tid & 7;
        const int ch = ocg * 32 + ocl;
        if (ch < OMC) {
            u16* dst = om_out + ((size_t)(n * NT + tile) * OMC + ch) * 256;
            const u16* srcr = tb + ocl * 264;
#pragma unroll
            for (int j = 0; j < 4; ++j) {
                int un = (q + j * 8) * 8;
                *(u32x4*)(dst + un) = *(const u32x4*)(srcr + un);
            }
        }
    }
}

// ---- modulated deformable conv; blocked om (fp16) + blocked feat (R12) ------
template<int LAST>
__global__ __launch_bounds__(256, 4) void deform_k(
    const u16* __restrict__ feat,  // [n][NT][8][256][8] fp16
    const u16* __restrict__ om,    // [n][NT][216][256] fp16
    const float* __restrict__ wgtp, const float* __restrict__ bias,
    u16* __restrict__ out_feat, float* __restrict__ out32)
{
    const int id = blockIdx.x;
    const int n = id & 7, w = id >> 3;
    const int tile = w >> 3, g = w & 7;        // tile-major, g fastest

    const int ty = threadIdx.x >> 4, tx = threadIdx.x & 15;
    const int h  = (tile / 6) * 16 + ty;
    const int wx = (tile % 6) * 16 + tx;
    const int pix = h * WDIM + wx;
    const int pixT = ty * 16 + tx;

    const float* wg = wgtp + (size_t)g * 576;
    const u16* ob = om + (size_t)(n * NT + tile) * OMC * 256;
    const u16* fbase = feat + (size_t)(n * NT) * 8 * 2048 + g * 2048;

    float acc[8];
#pragma unroll
    for (int o = 0; o < 8; ++o) acc[o] = 0.f;

#pragma unroll
    for (int k = 0; k < 9; ++k) {
        float dy = (float)b16f(ob[(g * 18 + 2 * k    ) * 256 + pixT]);
        float dx = (float)b16f(ob[(g * 18 + 2 * k + 1) * 256 + pixT]);
        float m  = (float)b16f(ob[(OFFCH + g * 9 + k) * 256 + pixT]);

        float py = dy + (float)(k / 3 - 1) + (float)h;
        float px = dx + (float)(k % 3 - 1) + (float)wx;
        float y0f = floorf(py), x0f = floorf(px);
        float ly = py - y0f, lx = px - x0f;
        int y0 = (int)y0f, x0 = (int)x0f;
        int y1 = y0 + 1,   x1 = x0 + 1;

        bool vy0 = (y0 >= 0) && (y0 < HDIM);
        bool vy1 = (y1 >= 0) && (y1 < HDIM);
        bool vx0 = (x0 >= 0) && (x0 < WDIM);
        bool vx1 = (x1 >= 0) && (x1 < WDIM);

        float w00 = (vy0 && vx0) ? (1.f - ly) * (1.f - lx) : 0.f;
        float w01 = (vy0 && vx1) ? (1.f - ly) * lx         : 0.f;
        float w10 = (vy1 && vx0) ? ly * (1.f - lx)         : 0.f;
        float w11 = (vy1 && vx1) ? ly * lx                 : 0.f;

        int y0c = min(max(y0, 0), HDIM - 1), y1c = min(max(y1, 0), HDIM - 1);
        int x0c = min(max(x0, 0), WDIM - 1), x1c = min(max(x1, 0), WDIM - 1);

        auto ga = [&](int y, int x) -> const f16x8* {
            int tof = (y >> 4) * 6 + (x >> 4);
            int pin = (y & 15) * 16 + (x & 15);
            return (const f16x8*)(fbase + (size_t)tof * 16384 + pin * 8);
        };
        f16x8 C00 = *ga(y0c, x0c);
        f16x8 C01 = *ga(y0c, x1c);
        f16x8 C10 = *ga(y1c, x0c);
        f16x8 C11 = *ga(y1c, x1c);

#pragma unroll
        for (int c = 0; c < 8; ++c) {
            float v =      w00 * (float)C00[c];
            v = fmaf(w01, (float)C01[c], v);
            v = fmaf(w10, (float)C10[c], v);
            v = fmaf(w11, (float)C11[c], v);
            v *= m;
            const float* w8 = wg + (k * 8 + c) * 8;
#pragma unroll
            for (int o = 0; o < 8; ++o)
                acc[o] = fmaf(w8[o], v, acc[o]);
        }
    }

    if (LAST) {
#pragma unroll
        for (int o = 0; o < 8; ++o)
            out32[((size_t)n * CF + g * 8 + o) * HW + pix] = acc[o] + bias[g * 8 + o];
    } else {
        u16 hb[8];
#pragma unroll
        for (int o = 0; o < 8; ++o)
            hb[o] = f16b((f16)(acc[o] + bias[g * 8 + o]));
        u32x4 hv;
        hv.x = (u32)hb[0] | ((u32)hb[1] << 16); hv.y = (u32)hb[2] | ((u32)hb[3] << 16);
        hv.z = (u32)hb[4] | ((u32)hb[5] << 16); hv.w = (u32)hb[6] | ((u32)hb[7] << 16);
        *(u32x4*)(out_feat + ((size_t)((n * NT + tile) * 8 + g) * 256 + pixT) * 8) = hv;
    }
}

// ---------------------------------------------------------------------------
extern "C" void kernel_launch(void* const* d_in, const int* in_sizes, int n_in,
                              void* d_out, int out_size, void* d_ws, size_t ws_size,
                              hipStream_t stream) {
    const float* burst = (const float*)d_in[0];
    const float* bw    = (const float*)d_in[1];

    const float* ow[4]; const float* dw[4]; const float* db[4];
    bool interleaved = (in_sizes[3] == 64 * 8 * 9);
    for (int i = 0; i < 4; ++i) {
        if (interleaved) {
            ow[i] = (const float*)d_in[2 + 3 * i];
            dw[i] = (const float*)d_in[3 + 3 * i];
            db[i] = (const float*)d_in[4 + 3 * i];
        } else {
            ow[i] = (const float*)d_in[2 + i];
            dw[i] = (const float*)d_in[6 + i];
            db[i] = (const float*)d_in[10 + i];
        }
    }

    float* out = (float*)d_out;

    // ws layout (~42.6 MB)
    u16*   om    = (u16*)d_ws;                     // 15,925,248 u16 (31.9MB)
    u16*   featB = om + 15925248;                  //  4,718,592 u16
    u16*   wp    = featB + 4718592;                //    589,824 u16
    float* dwp   = (float*)(wp + 589824);          //     18,432 f32
    u16*   cat   = (u16*)d_ws;                     //  9,437,184 u16 (alias om)
    u16*   featA = (u16*)d_out;                    //  4,718,592 u16 (alias d_out)

    const u16* wp_b = wp;
    const u16* wp_o[4];
    for (int i = 0; i < 4; ++i)
        wp_o[i] = wp + 73728 + (size_t)i * 129024;

    pack_w_k<<<dim3(512), dim3(256), 0, stream>>>(
        bw, ow[0], ow[1], ow[2], ow[3], dw[0], dw[1], dw[2], dw[3], wp, dwp);
    prep_cat_k<<<dim3(288), dim3(256), 0, stream>>>(burst, cat);

    // bottleneck: cat -> featA (d_out alias). 576 = 8 img x (36 tiles x 2 ocg)
    conv_mfma_k<16, 0><<<dim3(576), dim3(256), 0, stream>>>(
        cat, wp_b, nullptr, featA);

    // ping-pong: A -> B -> A -> B -> d_out(fp32)
    u16* fx = featA;
    u16* fy = featB;
    for (int i = 0; i < 4; ++i) {
        conv_mfma_k<8, 1><<<dim3(2016), dim3(256), 0, stream>>>(
            fx, wp_o[i], om, nullptr);
        if (i < 3) {
            deform_k<0><<<dim3(2304), dim3(256), 0, stream>>>(
                fx, om, dwp + (size_t)i * 4608, db[i], fy, nullptr);
            u16* t = fx; fx = fy; fy = t;
        } else {
            deform_k<1><<<dim3(2304), dim3(256), 0, stream>>>(
                fx, om, dwp + (size_t)i * 4608, db[i], nullptr, out);
        }
    }
}